// Round 9
// baseline (988.902 us; speedup 1.0000x reference)
//
#include <hip/hip_runtime.h>

#define T 1024
#define BATCH 512
#define EMB 64
#define HID 64
#define NGATE 256
#define VOCABP1 50001

typedef unsigned int uint32;
typedef unsigned short u16;
typedef __attribute__((ext_vector_type(8))) short short8;   // 8 bf16 = 4 VGPRs
typedef __attribute__((ext_vector_type(4))) float f32x4;    // MFMA C/D
typedef __attribute__((ext_vector_type(4))) uint32 uint4v;

__device__ __forceinline__ float rcpf(float x) { return __builtin_amdgcn_rcpf(x); }
__device__ __forceinline__ float sigm(float x) { return rcpf(1.0f + __expf(-x)); }
__device__ __forceinline__ float tanhfast(float x) { return 1.0f - 2.0f * rcpf(__expf(2.0f * x) + 1.0f); }
__device__ __forceinline__ float bcastf(float v, int k) {
    return __int_as_float(__builtin_amdgcn_readlane(__float_as_int(v), k));
}
__device__ __forceinline__ u16 f2bf(float x) {        // RNE f32->bf16
    uint32 u = __float_as_uint(x);
    u += 0x7fffu + ((u >> 16) & 1u);
    return (u16)(u >> 16);
}
__device__ __forceinline__ float bf2f(u16 h) { return __uint_as_float(((uint32)h) << 16); }
__device__ __forceinline__ short8 as_short8(uint4v v) {
    union { uint4v u; short8 s; } c; c.u = v; return c.s;
}

// LDS-only barrier: drains lgkmcnt (cross-wave DS visibility) but leaves
// global loads in flight across the barrier.
#define BARRIER_LDS() asm volatile("s_waitcnt lgkmcnt(0)\n\ts_barrier" ::: "memory")

// ---------------------------------------------------------------------------
// bf16 cast of the embedding table (6.4 MB L2/L3-resident gather target).
// ---------------------------------------------------------------------------
__global__ void embbf_kernel(const float* __restrict__ emb, u16* __restrict__ embbf)
{
    const int i = blockIdx.x * 256 + threadIdx.x;
    if (i < VOCABP1 * EMB) embbf[i] = f2bf(emb[i]);
}

// ---------------------------------------------------------------------------
// Step-ordered token streams + mask bit-words.
//   xs[d][b][s] = x[b][d ? T-1-s : s];  mbits[d][b][w] bit i = (xs[.., w*32+i] != 0)
// ---------------------------------------------------------------------------
__global__ void xsprep_kernel(const int* __restrict__ x, int* __restrict__ xs,
                              uint32* __restrict__ mbits)
{
    const int idx  = blockIdx.x * 256 + threadIdx.x;  // (d*512+b)*32 + word
    const int word = idx & 31;
    const int db   = idx >> 5;
    const int d    = db >> 9;
    const int b    = db & 511;
    const int* src = x + b * T;
    int* dst = xs + (size_t)db * T + word * 32;
    uint32 m = 0;
#pragma unroll 8
    for (int i = 0; i < 32; ++i) {
        const int t = word * 32 + i;
        const int v = src[d ? (T - 1 - t) : t];
        dst[i] = v;
        m |= (v != 0 ? 1u : 0u) << i;
    }
    mbits[idx] = m;
}

// ---------------------------------------------------------------------------
// B-fragment prep: var 0 = U-hi, 1 = U-lo, 2 = W-hi (single bf16 for x@W).
//   idx = ((((d*4+w)*4+g)*2+ks)*3+var)*512 + lane*8 + j
//   k = ks*32+(lane>>4)*8+j,  col = g*64+16w+(lane&15)
// ---------------------------------------------------------------------------
__global__ void bfrag_kernel(const float* __restrict__ Uf, const float* __restrict__ Ub,
                             const float* __restrict__ Wf, const float* __restrict__ Wb,
                             u16* __restrict__ bfrag)
{
    const int d = blockIdx.x;                 // 0 fwd, 1 bwd
    const float* U = d ? Ub : Uf;
    const float* W = d ? Wb : Wf;
    const int tid = threadIdx.x, lane = tid & 63, w = tid >> 6;
#pragma unroll
    for (int g = 0; g < 4; ++g)
#pragma unroll
    for (int ks = 0; ks < 2; ++ks)
#pragma unroll
    for (int j = 0; j < 8; ++j) {
        const int col = g * 64 + 16 * w + (lane & 15);
        const int k   = ks * 32 + (lane >> 4) * 8 + j;
        const float uv = U[k * NGATE + col];
        const u16 uhi = f2bf(uv);
        const u16 ulo = f2bf(uv - bf2f(uhi));
        const u16 whi = f2bf(W[k * NGATE + col]);
        const size_t base = ((((size_t)(d * 4 + w) * 4 + g) * 2 + ks) * 3) * 512;
        bfrag[base + 0 * 512 + lane * 8 + j] = uhi;
        bfrag[base + 1 * 512 + lane * 8 + j] = ulo;
        bfrag[base + 2 * 512 + lane * 8 + j] = whi;
    }
}

// ---------------------------------------------------------------------------
// MFMA LSTM. R8 failure: same-step token load->LDS store forced vmcnt(0)
// every step (~1500 stall cyc/step). Now: masks = bit-words in regs (32-step
// refill), token values = int4 reg ring (5-step lead), emb gather 2 steps
// deep (load s -> LDS s+2 -> MFMA s+3). LDS banking: h frags packed hi|lo
// u32, stride-9 rows (~conflict-free); emb frags stride-5 u32 rows.
// ---------------------------------------------------------------------------
__global__ __launch_bounds__(256, 1)
void lstm_mfma(const int* __restrict__ xs,
               const uint32* __restrict__ mbits,
               const u16* __restrict__ embbf,
               const u16* __restrict__ bfragp,
               const float* __restrict__ bf, const float* __restrict__ bb,
               float* __restrict__ hcat)
{
    const int tid  = threadIdx.x;
    const int lane = tid & 63;
    const int w    = tid >> 6;          // unit group
    const int col  = lane & 15;
    const int quad = lane >> 4;
    const int d    = blockIdx.x >> 5;
    const int gb   = blockIdx.x & 31;   // batch group

    const int ucol = 16 * w + col;
    const int KS   = w >> 1;
    const int q2   = (2 * w + (col >> 3)) & 3;

    // gather role: seq mseq, 8-byte segment pseg of its emb row
    const int mseq = tid & 15;
    const int pseg = tid >> 4;                  // 0..15
    const int ks_w = pseg >> 3;
    const int qw   = (pseg >> 1) & 3;
    const int jh   = pseg & 1;

    // B fragments: U hi/lo + W hi (AGPR-resident, MFMA reads natively)
    short8 Bf[4][2][2];
    short8 Bx[4][2];
    {
        const u16* pb = bfragp + (size_t)(d * 4 + w) * 4 * 2 * 3 * 512;
#pragma unroll
        for (int g = 0; g < 4; ++g)
#pragma unroll
        for (int ks = 0; ks < 2; ++ks) {
            Bf[g][ks][0] = *(const short8*)&pb[((g * 2 + ks) * 3 + 0) * 512 + lane * 8];
            Bf[g][ks][1] = *(const short8*)&pb[((g * 2 + ks) * 3 + 1) * 512 + lane * 8];
            Bx[g][ks]    = *(const short8*)&pb[((g * 2 + ks) * 3 + 2) * 512 + lane * 8];
        }
    }
    float biasv[4];
    {
        const float* bias = d ? bb : bf;
#pragma unroll
        for (int g = 0; g < 4; ++g) biasv[g] = bias[g * 64 + ucol];
    }

    // h frags: packed (hi | lo<<16) u32, stride-9 rows -> ~conflict-free
    __shared__ uint32 AhP[2][2][64][9];   // [buf][ks][row][j<8 + pad]
    // emb frags: u32 pairs (2 bf16 each), stride-5 rows -> conflict-free
    __shared__ uint32 AxP[2][2][64][5];   // [buf][ks][row][c<4 + pad]

    {   // zero h_{-1} (both buffers)
        uint32* f = &AhP[0][0][0][0];
        for (int i = tid; i < 2 * 2 * 64 * 9; i += 256) f[i] = 0;
    }

    const int*  xrow  = xs + (size_t)(d * 512 + gb * 16 + mseq) * T;
    const int4* xrow4 = (const int4*)xrow;
    const uint32* mrow[4];
#pragma unroll
    for (int r = 0; r < 4; ++r)
        mrow[r] = mbits + (size_t)(d * 512 + gb * 16 + quad * 4 + r) * 32;

    // register pipelines
    int4 tc0 = xrow4[0], tc1 = xrow4[1];            // token chunks 0,1
    uint32 mcur[4], mnext[4];
#pragma unroll
    for (int r = 0; r < 4; ++r) { mcur[r] = mrow[r][0]; mnext[r] = mrow[r][1]; }

    typedef struct { uint32 x, y; } u32x2;
    u32x2 er[2];
    {   // warmup: step0 emb -> LDS buf0; step1 -> er[0]; step2 -> er[1]
        const u32x2 e0 = *(const u32x2*)(embbf + (size_t)tc0.x * EMB + pseg * 4);
        er[0]          = *(const u32x2*)(embbf + (size_t)tc0.y * EMB + pseg * 4);
        er[1]          = *(const u32x2*)(embbf + (size_t)tc0.z * EMB + pseg * 4);
        AxP[0][ks_w][qw * 16 + mseq][jh * 2 + 0] = e0.x;
        AxP[0][ks_w][qw * 16 + mseq][jh * 2 + 1] = e0.y;
    }
    __syncthreads();    // once, outside hot loop

    float hv[4] = {0.f, 0.f, 0.f, 0.f};
    float cv[4] = {0.f, 0.f, 0.f, 0.f};

#define STEP(SV, P, PREF)                                                      \
  {                                                                            \
    BARRIER_LDS();                                                             \
    /* ---- h frag reads + unpack (hi|lo packed u32) ---- */                   \
    uint32 hw0[8], hw1[8];                                                     \
    _Pragma("unroll")                                                          \
    for (int c = 0; c < 8; ++c) hw0[c] = AhP[1 - (P)][0][lane][c];             \
    _Pragma("unroll")                                                          \
    for (int c = 0; c < 8; ++c) hw1[c] = AhP[1 - (P)][1][lane][c];             \
    uint4v hi0v, lo0v, hi1v, lo1v;                                             \
    _Pragma("unroll")                                                          \
    for (int c = 0; c < 4; ++c) {                                              \
      hi0v[c] = (hw0[2 * c] & 0xffffu) | (hw0[2 * c + 1] << 16);               \
      lo0v[c] = (hw0[2 * c] >> 16) | (hw0[2 * c + 1] & 0xffff0000u);           \
      hi1v[c] = (hw1[2 * c] & 0xffffu) | (hw1[2 * c + 1] << 16);               \
      lo1v[c] = (hw1[2 * c] >> 16) | (hw1[2 * c + 1] & 0xffff0000u);           \
    }                                                                          \
    const short8 Ah0 = as_short8(hi0v), Al0 = as_short8(lo0v);                 \
    const short8 Ah1 = as_short8(hi1v), Al1 = as_short8(lo1v);                 \
    /* ---- emb frag reads (no unpack needed) ---- */                          \
    uint4v xw0, xw1;                                                           \
    _Pragma("unroll")                                                          \
    for (int c = 0; c < 4; ++c) { xw0[c] = AxP[(P)][0][lane][c];               \
                                  xw1[c] = AxP[(P)][1][lane][c]; }             \
    const short8 Ax0 = as_short8(xw0), Ax1 = as_short8(xw1);                   \
    /* ---- gather pipeline: token[SV+3] ---- */                               \
    {                                                                          \
      const int i3 = (SV) + 3;                                                 \
      const int4 tcs = (((i3 >> 2) & 1) ? tc1 : tc0);                          \
      const int tlo = (i3 & 1) ? tcs.y : tcs.x;                                \
      const int thi = (i3 & 1) ? tcs.w : tcs.z;                                \
      const int tg  = (i3 & 2) ? thi : tlo;                                    \
      AxP[1 - (P)][ks_w][qw * 16 + mseq][jh * 2 + 0] = er[(P)].x;              \
      AxP[1 - (P)][ks_w][qw * 16 + mseq][jh * 2 + 1] = er[(P)].y;              \
      er[(P)] = *(const u32x2*)(embbf + (size_t)tg * EMB + pseg * 4);          \
    }                                                                          \
    if ((PREF) && (((SV) & 3) == 0)) {       /* token chunk refill */          \
      const int ci = (SV) >> 2;                                                \
      const int cl = (ci + 2 < 256) ? (ci + 2) : 255;                          \
      const int4 nc = xrow4[cl];                                               \
      if (ci & 1) tc1 = nc; else tc0 = nc;                                     \
    }                                                                          \
    if ((PREF) && (((SV) & 31) == 0) && ((SV) > 0)) {   /* mask window */      \
      const int wn = ((SV) >> 5) + 1;                                          \
      const int wc = (wn < 32) ? wn : 31;                                      \
      _Pragma("unroll")                                                        \
      for (int r = 0; r < 4; ++r) { mcur[r] = mnext[r]; mnext[r] = mrow[r][wc]; } \
    }                                                                          \
    /* ---- MFMAs ---- */                                                      \
    f32x4 acc[4];                                                              \
    _Pragma("unroll")                                                          \
    for (int g = 0; g < 4; ++g) {                                              \
      acc[g][0] = biasv[g]; acc[g][1] = biasv[g];                              \
      acc[g][2] = biasv[g]; acc[g][3] = biasv[g];                              \
      acc[g] = __builtin_amdgcn_mfma_f32_16x16x32_bf16(Ax0, Bx[g][0],    acc[g], 0, 0, 0); \
      acc[g] = __builtin_amdgcn_mfma_f32_16x16x32_bf16(Ax1, Bx[g][1],    acc[g], 0, 0, 0); \
      acc[g] = __builtin_amdgcn_mfma_f32_16x16x32_bf16(Ah0, Bf[g][0][0], acc[g], 0, 0, 0); \
      acc[g] = __builtin_amdgcn_mfma_f32_16x16x32_bf16(Ah1, Bf[g][1][0], acc[g], 0, 0, 0); \
      acc[g] = __builtin_amdgcn_mfma_f32_16x16x32_bf16(Ah0, Bf[g][0][1], acc[g], 0, 0, 0); \
      acc[g] = __builtin_amdgcn_mfma_f32_16x16x32_bf16(Ah1, Bf[g][1][1], acc[g], 0, 0, 0); \
      acc[g] = __builtin_amdgcn_mfma_f32_16x16x32_bf16(Al0, Bf[g][0][0], acc[g], 0, 0, 0); \
      acc[g] = __builtin_amdgcn_mfma_f32_16x16x32_bf16(Al1, Bf[g][1][0], acc[g], 0, 0, 0); \
    }                                                                          \
    /* ---- epilogue ---- */                                                   \
    _Pragma("unroll")                                                          \
    for (int r = 0; r < 4; ++r) {                                              \
      const float iv = sigm(acc[0][r]);                                        \
      const float fv = sigm(acc[1][r]);                                        \
      const float gv = tanhfast(acc[2][r]);                                    \
      const float ov = sigm(acc[3][r]);                                        \
      const float cn = fmaf(fv, cv[r], iv * gv);                               \
      const float hn = ov * tanhfast(cn);                                      \
      if ((mcur[r] >> ((SV) & 31)) & 1) { cv[r] = cn; hv[r] = hn; }            \
      const uint32 uh = __float_as_uint(hv[r]);                                \
      const u16 hhi = (u16)(uh >> 16);            /* trunc: err lands in lo */ \
      const u16 hlo = f2bf(hv[r] - bf2f(hhi));                                 \
      AhP[(P)][KS][q2 * 16 + quad * 4 + r][col & 7] =                          \
          (uint32)hhi | ((uint32)hlo << 16);                                   \
    }                                                                          \
  }

    for (int s = 0; s < T; s += 2) {
        STEP(s, 0, 1)
        STEP(s + 1, 1, 0)
    }
#undef STEP

#pragma unroll
    for (int r = 0; r < 4; ++r)
        hcat[(size_t)(gb * 16 + quad * 4 + r) * (2 * HID) + d * HID + ucol] = hv[r];
}

// ---------------------------------------------------------------------------
// Tiny MLP head: out[b] = relu(hcat[b] @ W1 + b1) @ W2 + b2
// ---------------------------------------------------------------------------
__global__ void mlp_kernel(const float* __restrict__ hcat,
                           const float* __restrict__ W1, const float* __restrict__ b1,
                           const float* __restrict__ W2, const float* __restrict__ b2,
                           float* __restrict__ out)
{
    const int b = blockIdx.x;
    const int tid = threadIdx.x;  // 64 threads
    __shared__ float h1[32];
    const float* h = hcat + b * (2 * HID);
    if (tid < 32) {
        float acc = b1[tid];
#pragma unroll
        for (int k = 0; k < 2 * HID; ++k) acc += h[k] * W1[k * 32 + tid];
        h1[tid] = fmaxf(acc, 0.0f);
    }
    __syncthreads();
    if (tid == 0) {
        float acc = b2[0];
#pragma unroll
        for (int m = 0; m < 32; ++m) acc += h1[m] * W2[m];
        out[b] = acc;
    }
}

extern "C" void kernel_launch(void* const* d_in, const int* in_sizes, int n_in,
                              void* d_out, int out_size, void* d_ws, size_t ws_size,
                              hipStream_t stream)
{
    const int*   x   = (const int*)d_in[0];
    const float* emb = (const float*)d_in[1];
    const float* Wf  = (const float*)d_in[2];
    const float* Uf  = (const float*)d_in[3];
    const float* bf  = (const float*)d_in[4];
    const float* Wb  = (const float*)d_in[5];
    const float* Ub  = (const float*)d_in[6];
    const float* bb  = (const float*)d_in[7];
    const float* W1  = (const float*)d_in[8];
    const float* b1  = (const float*)d_in[9];
    const float* W2  = (const float*)d_in[10];
    const float* b2  = (const float*)d_in[11];
    float* out = (float*)d_out;

    // workspace: [xs | mbits | hcat | bfrag | embbf]
    int*    xs     = (int*)d_ws;                        // 2*512*1024 i32
    uint32* mbits  = (uint32*)(xs + 2 * 512 * 1024);    // 2*512*32 u32
    float*  hcat   = (float*)(mbits + 2 * 512 * 32);    // 512*128 f32
    u16*    bfragp = (u16*)(hcat + 512 * 128);          // 98304 u16
    u16*    embbf  = bfragp + 98304;                    // 50001*64 bf16

    embbf_kernel<<<dim3((VOCABP1 * EMB + 255) / 256), dim3(256), 0, stream>>>(emb, embbf);
    xsprep_kernel<<<dim3(2 * 512 * 32 / 256), dim3(256), 0, stream>>>(x, xs, mbits);
    bfrag_kernel<<<dim3(2), dim3(256), 0, stream>>>(Uf, Ub, Wf, Wb, bfragp);
    lstm_mfma<<<dim3(64), dim3(256), 0, stream>>>(xs, mbits, embbf, bfragp, bf, bb, hcat);
    mlp_kernel<<<dim3(BATCH), dim3(64), 0, stream>>>(hcat, W1, b1, W2, b2, out);
}

// Round 10
// 823.603 us; speedup vs baseline: 1.2007x; 1.2007x over previous
//
#include <hip/hip_runtime.h>

#define T 1024
#define BATCH 512
#define EMB 64
#define HID 64
#define NGATE 256
#define VOCABP1 50001

typedef unsigned int uint32;
typedef unsigned short u16;
typedef __attribute__((ext_vector_type(8))) short short8;   // 8 bf16 = 4 VGPRs
typedef __attribute__((ext_vector_type(4))) float f32x4;    // MFMA C/D

__device__ __forceinline__ float rcpf(float x) { return __builtin_amdgcn_rcpf(x); }
__device__ __forceinline__ float sigm(float x) { return rcpf(1.0f + __expf(-x)); }
__device__ __forceinline__ float tanhfast(float x) { return 1.0f - 2.0f * rcpf(__expf(2.0f * x) + 1.0f); }
__device__ __forceinline__ u16 f2bf(float x) {        // RNE f32->bf16
    uint32 u = __float_as_uint(x);
    u += 0x7fffu + ((u >> 16) & 1u);
    return (u16)(u >> 16);
}
__device__ __forceinline__ float bf2f(u16 h) { return __uint_as_float(((uint32)h) << 16); }

// LDS-only barrier: drains lgkmcnt (cross-wave DS visibility) but leaves
// global loads in flight across the barrier.
#define BARRIER_LDS() asm volatile("s_waitcnt lgkmcnt(0)\n\ts_barrier" ::: "memory")

// ---------------------------------------------------------------------------
// bf16 cast of the embedding table (6.4 MB, gather target for the prep pass).
// ---------------------------------------------------------------------------
__global__ void embbf_kernel(const float* __restrict__ emb, u16* __restrict__ embbf)
{
    const int i = blockIdx.x * 256 + threadIdx.x;
    if (i < VOCABP1 * EMB) embbf[i] = f2bf(emb[i]);
}

// ---------------------------------------------------------------------------
// Mask bit-words: mbits[d][b][w] bit i = (x_step(d,b,w*32+i) != 0)
// ---------------------------------------------------------------------------
__global__ void maskprep_kernel(const int* __restrict__ x, uint32* __restrict__ mbits)
{
    const int idx  = blockIdx.x * 256 + threadIdx.x;  // (d*512+b)*32 + word
    const int word = idx & 31;
    const int db   = idx >> 5;
    const int d    = db >> 9;
    const int b    = db & 511;
    const int* src = x + b * T;
    uint32 m = 0;
#pragma unroll 8
    for (int i = 0; i < 32; ++i) {
        const int t = word * 32 + i;
        m |= (src[d ? (T - 1 - t) : t] != 0 ? 1u : 0u) << i;
    }
    mbits[idx] = m;
}

// ---------------------------------------------------------------------------
// A-fragment emb stream (ONE stream serves both directions: bwd reads
// chunk 1023-s).  xstream[gb][t][ks*64+lane][j] = embbf[x[gb*16+(lane&15)][t]]
//                                                     [ks*32+(lane>>4)*8+j]
// 2 KB per (gb,t) chunk, 64 MB total. Fully parallel gather -> stream write.
// ---------------------------------------------------------------------------
__global__ void xstream_kernel(const int* __restrict__ x,
                               const u16* __restrict__ embbf,
                               u16* __restrict__ xstream)
{
    const int gb    = blockIdx.x >> 6;          // 0..31
    const int stile = blockIdx.x & 63;          // 16 steps per block
    const int tid   = threadIdx.x;
    const int lane  = tid & 63;
    const int half  = tid >> 6;                 // 0..3
    const int ks    = half & 1;
    const int sp    = half >> 1;                // 0,1
    const int m     = lane & 15;
    const int qj    = (lane >> 4) * 8;
#pragma unroll
    for (int i = 0; i < 8; ++i) {
        const int s   = stile * 16 + sp * 8 + i;
        const int tok = x[(gb * 16 + m) * T + s];
        const short8 v = *(const short8*)(embbf + (size_t)tok * EMB + ks * 32 + qj);
        *(short8*)(xstream + ((size_t)(gb * 1024 + s) * 128 + ks * 64 + lane) * 8) = v;
    }
}

// ---------------------------------------------------------------------------
// B-fragment prep: var 0 = U-hi, 1 = U-lo, 2 = W-hi (single bf16 for x@W).
//   idx = ((((d*4+w)*4+g)*2+ks)*3+var)*512 + lane*8 + j
// ---------------------------------------------------------------------------
__global__ void bfrag_kernel(const float* __restrict__ Uf, const float* __restrict__ Ub,
                             const float* __restrict__ Wf, const float* __restrict__ Wb,
                             u16* __restrict__ bfrag)
{
    const int d = blockIdx.x;
    const float* U = d ? Ub : Uf;
    const float* W = d ? Wb : Wf;
    const int tid = threadIdx.x, lane = tid & 63, w = tid >> 6;
#pragma unroll
    for (int g = 0; g < 4; ++g)
#pragma unroll
    for (int ks = 0; ks < 2; ++ks)
#pragma unroll
    for (int j = 0; j < 8; ++j) {
        const int col = g * 64 + 16 * w + (lane & 15);
        const int k   = ks * 32 + (lane >> 4) * 8 + j;
        const float uv = U[k * NGATE + col];
        const u16 uhi = f2bf(uv);
        const u16 ulo = f2bf(uv - bf2f(uhi));
        const u16 whi = f2bf(W[k * NGATE + col]);
        const size_t base = ((((size_t)(d * 4 + w) * 4 + g) * 2 + ks) * 3) * 512;
        bfrag[base + 0 * 512 + lane * 8 + j] = uhi;
        bfrag[base + 1 * 512 + lane * 8 + j] = ulo;
        bfrag[base + 2 * 512 + lane * 8 + j] = whi;
    }
}

// ---------------------------------------------------------------------------
// MFMA LSTM. R10: zero gather — the A-frag emb stream is precomputed, so the
// per-step global traffic is 2 coalesced b128 register loads consumed 2 steps
// later. No LDS staging of global data, no tokens, no unpack. x-part MFMAs
// issue BEFORE the barrier (register-only), covering barrier wait.
// ---------------------------------------------------------------------------
__global__ __launch_bounds__(256, 1)
void lstm_mfma(const uint32* __restrict__ mbits,
               const u16* __restrict__ xstream,
               const u16* __restrict__ bfragp,
               const float* __restrict__ bf, const float* __restrict__ bb,
               float* __restrict__ hcat)
{
    const int tid  = threadIdx.x;
    const int lane = tid & 63;
    const int w    = tid >> 6;          // unit group
    const int col  = lane & 15;
    const int quad = lane >> 4;
    const int d    = blockIdx.x >> 5;
    const int gb   = blockIdx.x & 31;

    const int ucol = 16 * w + col;
    const int KS   = w >> 1;
    const int q2   = (2 * w + (col >> 3)) & 3;

    // B fragments (AGPR-resident, MFMA reads natively)
    short8 BU[4][2][2];   // [g][ks][hi/lo]
    short8 BW[4][2];      // [g][ks]
    {
        const u16* pb = bfragp + (size_t)(d * 4 + w) * 4 * 2 * 3 * 512;
#pragma unroll
        for (int g = 0; g < 4; ++g)
#pragma unroll
        for (int ks = 0; ks < 2; ++ks) {
            BU[g][ks][0] = *(const short8*)&pb[((g * 2 + ks) * 3 + 0) * 512 + lane * 8];
            BU[g][ks][1] = *(const short8*)&pb[((g * 2 + ks) * 3 + 1) * 512 + lane * 8];
            BW[g][ks]    = *(const short8*)&pb[((g * 2 + ks) * 3 + 2) * 512 + lane * 8];
        }
    }
    float biasv[4];
    {
        const float* bias = d ? bb : bf;
#pragma unroll
        for (int g = 0; g < 4; ++g) biasv[g] = bias[g * 64 + ucol];
    }

    __shared__ u16 Ahi[2][2][64][8];   // [buf][ks][row][j]  16B rows, b128-aligned
    __shared__ u16 Alo[2][2][64][8];
    {
        u16* f = &Ahi[0][0][0][0];
        for (int i = tid; i < 2 * 2 * 64 * 8; i += 256) f[i] = 0;
        u16* f2 = &Alo[0][0][0][0];
        for (int i = tid; i < 2 * 2 * 64 * 8; i += 256) f2[i] = 0;
    }

    const uint32* mrow[4];
#pragma unroll
    for (int r = 0; r < 4; ++r)
        mrow[r] = mbits + (size_t)(d * 512 + gb * 16 + quad * 4 + r) * 32;
    uint32 mcur[4], mnext[4];
#pragma unroll
    for (int r = 0; r < 4; ++r) { mcur[r] = mrow[r][0]; mnext[r] = mrow[r][1]; }

    const u16* sptr = xstream + (size_t)gb * 1024 * 1024;   // this gb's stream

    // stream ring: ax[phase][ks], warmup steps 0,1
    short8 axr[2][2];
    {
        const int c0 = d ? 1023 : 0;
        const int c1 = d ? 1022 : 1;
        axr[0][0] = *(const short8*)(sptr + (size_t)c0 * 1024 + lane * 8);
        axr[0][1] = *(const short8*)(sptr + (size_t)c0 * 1024 + 512 + lane * 8);
        axr[1][0] = *(const short8*)(sptr + (size_t)c1 * 1024 + lane * 8);
        axr[1][1] = *(const short8*)(sptr + (size_t)c1 * 1024 + 512 + lane * 8);
    }
    __syncthreads();    // once, outside hot loop

    float hv[4] = {0.f, 0.f, 0.f, 0.f};
    float cv[4] = {0.f, 0.f, 0.f, 0.f};

#define STEP(SV, P, PREF)                                                      \
  {                                                                            \
    /* ---- x-part: register-only, before barrier ---- */                      \
    f32x4 acc[4];                                                              \
    _Pragma("unroll")                                                          \
    for (int g = 0; g < 4; ++g) {                                              \
      acc[g][0] = biasv[g]; acc[g][1] = biasv[g];                              \
      acc[g][2] = biasv[g]; acc[g][3] = biasv[g];                              \
      acc[g] = __builtin_amdgcn_mfma_f32_16x16x32_bf16(axr[P][0], BW[g][0], acc[g], 0, 0, 0); \
      acc[g] = __builtin_amdgcn_mfma_f32_16x16x32_bf16(axr[P][1], BW[g][1], acc[g], 0, 0, 0); \
    }                                                                          \
    /* ---- ring refill for step SV+2 (consumed 2 steps later) ---- */         \
    {                                                                          \
      const int cs = ((SV) + 2 <= 1023) ? ((SV) + 2) : 1023;                   \
      const int c2 = d ? (1023 - cs) : cs;                                     \
      const u16* cp = sptr + (size_t)c2 * 1024;                                \
      axr[P][0] = *(const short8*)(cp + lane * 8);                             \
      axr[P][1] = *(const short8*)(cp + 512 + lane * 8);                       \
    }                                                                          \
    if ((PREF) && (((SV) & 31) == 0) && ((SV) > 0)) {   /* mask window */      \
      const int wn = ((SV) >> 5) + 1;                                          \
      const int wc = (wn < 32) ? wn : 31;                                      \
      _Pragma("unroll")                                                        \
      for (int r = 0; r < 4; ++r) { mcur[r] = mnext[r]; mnext[r] = mrow[r][wc]; } \
    }                                                                          \
    BARRIER_LDS();                                                             \
    /* ---- h-part ---- */                                                     \
    const short8 Hh0 = *(const short8*)&Ahi[1 - (P)][0][lane][0];              \
    const short8 Hh1 = *(const short8*)&Ahi[1 - (P)][1][lane][0];              \
    const short8 Hl0 = *(const short8*)&Alo[1 - (P)][0][lane][0];              \
    const short8 Hl1 = *(const short8*)&Alo[1 - (P)][1][lane][0];              \
    _Pragma("unroll")                                                          \
    for (int g = 0; g < 4; ++g) {                                              \
      acc[g] = __builtin_amdgcn_mfma_f32_16x16x32_bf16(Hh0, BU[g][0][0], acc[g], 0, 0, 0); \
      acc[g] = __builtin_amdgcn_mfma_f32_16x16x32_bf16(Hh1, BU[g][1][0], acc[g], 0, 0, 0); \
      acc[g] = __builtin_amdgcn_mfma_f32_16x16x32_bf16(Hh0, BU[g][0][1], acc[g], 0, 0, 0); \
      acc[g] = __builtin_amdgcn_mfma_f32_16x16x32_bf16(Hh1, BU[g][1][1], acc[g], 0, 0, 0); \
      acc[g] = __builtin_amdgcn_mfma_f32_16x16x32_bf16(Hl0, BU[g][0][0], acc[g], 0, 0, 0); \
      acc[g] = __builtin_amdgcn_mfma_f32_16x16x32_bf16(Hl1, BU[g][1][0], acc[g], 0, 0, 0); \
    }                                                                          \
    /* ---- epilogue ---- */                                                   \
    _Pragma("unroll")                                                          \
    for (int r = 0; r < 4; ++r) {                                              \
      const float iv = sigm(acc[0][r]);                                        \
      const float fv = sigm(acc[1][r]);                                        \
      const float gv = tanhfast(acc[2][r]);                                    \
      const float ov = sigm(acc[3][r]);                                        \
      const float cn = fmaf(fv, cv[r], iv * gv);                               \
      const float hn = ov * tanhfast(cn);                                      \
      if ((mcur[r] >> ((SV) & 31)) & 1) { cv[r] = cn; hv[r] = hn; }            \
      const uint32 uh = __float_as_uint(hv[r]);                                \
      const u16 hhi = (u16)(uh >> 16);                                         \
      const u16 hlo = f2bf(hv[r] - bf2f(hhi));                                 \
      Ahi[(P)][KS][q2 * 16 + quad * 4 + r][col & 7] = hhi;                     \
      Alo[(P)][KS][q2 * 16 + quad * 4 + r][col & 7] = hlo;                     \
    }                                                                          \
  }

    for (int s = 0; s < T; s += 2) {
        STEP(s, 0, 1)
        STEP(s + 1, 1, 0)
    }
#undef STEP

#pragma unroll
    for (int r = 0; r < 4; ++r)
        hcat[(size_t)(gb * 16 + quad * 4 + r) * (2 * HID) + d * HID + ucol] = hv[r];
}

// ---------------------------------------------------------------------------
// Tiny MLP head: out[b] = relu(hcat[b] @ W1 + b1) @ W2 + b2
// ---------------------------------------------------------------------------
__global__ void mlp_kernel(const float* __restrict__ hcat,
                           const float* __restrict__ W1, const float* __restrict__ b1,
                           const float* __restrict__ W2, const float* __restrict__ b2,
                           float* __restrict__ out)
{
    const int b = blockIdx.x;
    const int tid = threadIdx.x;  // 64 threads
    __shared__ float h1[32];
    const float* h = hcat + b * (2 * HID);
    if (tid < 32) {
        float acc = b1[tid];
#pragma unroll
        for (int k = 0; k < 2 * HID; ++k) acc += h[k] * W1[k * 32 + tid];
        h1[tid] = fmaxf(acc, 0.0f);
    }
    __syncthreads();
    if (tid == 0) {
        float acc = b2[0];
#pragma unroll
        for (int m = 0; m < 32; ++m) acc += h1[m] * W2[m];
        out[b] = acc;
    }
}

extern "C" void kernel_launch(void* const* d_in, const int* in_sizes, int n_in,
                              void* d_out, int out_size, void* d_ws, size_t ws_size,
                              hipStream_t stream)
{
    const int*   x   = (const int*)d_in[0];
    const float* emb = (const float*)d_in[1];
    const float* Wf  = (const float*)d_in[2];
    const float* Uf  = (const float*)d_in[3];
    const float* bf  = (const float*)d_in[4];
    const float* Wb  = (const float*)d_in[5];
    const float* Ub  = (const float*)d_in[6];
    const float* bb  = (const float*)d_in[7];
    const float* W1  = (const float*)d_in[8];
    const float* b1  = (const float*)d_in[9];
    const float* W2  = (const float*)d_in[10];
    const float* b2  = (const float*)d_in[11];
    float* out = (float*)d_out;

    // workspace: [xstream 64MB | embbf | mbits | bfrag | hcat]  (~71 MB)
    u16*    xstream = (u16*)d_ws;                           // 32*1024*128*8 u16
    u16*    embbf   = xstream + (size_t)32 * 1024 * 1024;   // 50001*64 bf16
    uint32* mbits   = (uint32*)(embbf + 3200064);           // 2*512*32 u32
    u16*    bfragp  = (u16*)(mbits + 2 * 512 * 32);         // 98304 u16
    float*  hcat    = (float*)(bfragp + 98304);             // 512*128 f32

    embbf_kernel<<<dim3((VOCABP1 * EMB + 255) / 256), dim3(256), 0, stream>>>(emb, embbf);
    maskprep_kernel<<<dim3(2 * 512 * 32 / 256), dim3(256), 0, stream>>>(x, mbits);
    bfrag_kernel<<<dim3(2), dim3(256), 0, stream>>>(Uf, Ub, Wf, Wb, bfragp);
    xstream_kernel<<<dim3(32 * 64), dim3(256), 0, stream>>>(x, embbf, xstream);
    lstm_mfma<<<dim3(64), dim3(256), 0, stream>>>(mbits, xstream, bfragp, bf, bb, hcat);
    mlp_kernel<<<dim3(BATCH), dim3(64), 0, stream>>>(hcat, W1, b1, W2, b2, out);
}